// Round 10
// baseline (190.683 us; speedup 1.0000x reference)
//
#include <hip/hip_runtime.h>

// 2-layer GAT forward, N nodes, K=16 neighbors (row-sorted, exactly 16/dst),
// feats 128 -> 64 -> 64, fp32 in/out.
//
// K1: h1 = x @ W1 (fp16 MFMA) + scores s1a,s2a
// K2: attn(h1) -> xm fp16     [4 nodes/wave; gathers issued BEFORE softmax]
// K3: h2 = xm @ W2 + scores   [B operand entirely in registers]
// K4: attn(h2) -> out fp32
//
// Measured structure notes:
//  - R6: fusing attn+gemm cost occupancy (13%) -> net zero. Keep de-fused.
//  - R7: __launch_bounds__(256,4) strangled VGPRs -> serialized prefetch,
//    2.8x gemm1 regression. Keep (256,2) + 48-rows-upfront loads.
//  - R8: W-lo correction dropped; absmax 1.95e-3 vs 5.66e-3 threshold. BEST=184.3.
//  - R9: 8-node/wave attn (120 VGPR) halved occupancy -> +6 us. Latency-bound
//    attn wants TLP, not per-wave MLP. Back to 4-node shape.
//  - R10: single isolated change vs R8 — row-gathers issued before the
//    s2/softmax chain (srck depends only on col-bpermute).

typedef __attribute__((ext_vector_type(8))) _Float16 f16x8;
typedef __attribute__((ext_vector_type(4))) _Float16 f16x4;
typedef __attribute__((ext_vector_type(4))) float floatx4;

static __device__ inline float ubitf(unsigned u) { union { unsigned u; float f; } v; v.u = u; return v.f; }
static __device__ inline unsigned fbitu(float f) { union { float f; unsigned u; } v; v.f = f; return v.u; }

// ---------------- K1: h1 = X(fp32)[n,128] @ W1 -> fp16 + scores -------------
template<int KD>
__global__ __launch_bounds__(256, 2) void gemm_score_f16(
    const float* __restrict__ X, const float* __restrict__ W,
    const float* __restrict__ av, _Float16* __restrict__ H,
    float* __restrict__ s1, float* __restrict__ s2, int n)
{
    constexpr int NKT = KD / 32;
    constexpr int NF = NKT * 4 * 64;
    __shared__ f16x8 Bs[NF];
    const int tid = threadIdx.x;

    for (int f = tid; f < NF; f += 256) {
        const int ln = f & 63, ntk = f >> 6;
        const int kt = ntk >> 2, nt = ntk & 3;
        const int kbase = kt * 32 + (ln >> 4) * 8;
        const int ccol = nt * 16 + (ln & 15);
        f16x8 hh;
#pragma unroll
        for (int j = 0; j < 8; j++)
            hh[j] = (_Float16)W[(kbase + j) * 64 + ccol];
        Bs[f] = hh;
    }
    __syncthreads();

    const int wave = tid >> 6, lane = tid & 63;
    const int quad = lane >> 4, l15 = lane & 15;
    const int r0 = blockIdx.x * 192 + wave * 48;

    float a1c[4], a2c[4];
#pragma unroll
    for (int nt = 0; nt < 4; nt++) {
        a1c[nt] = av[nt * 16 + l15];
        a2c[nt] = av[64 + nt * 16 + l15];
    }

    float4 raw[NKT][3][2];
#pragma unroll
    for (int rb = 0; rb < 3; rb++) {
        int ra = r0 + rb * 16 + l15; if (ra > n - 1) ra = n - 1;
        const float* xp = &X[(size_t)ra * KD + quad * 8];
#pragma unroll
        for (int kt = 0; kt < NKT; kt++) {
            raw[kt][rb][0] = *(const float4*)(xp + kt * 32);
            raw[kt][rb][1] = *(const float4*)(xp + kt * 32 + 4);
        }
    }
    f16x8 A[NKT][3];
#pragma unroll
    for (int kt = 0; kt < NKT; kt++)
#pragma unroll
        for (int rb = 0; rb < 3; rb++) {
            f16x8 a;
            a[0] = (_Float16)raw[kt][rb][0].x; a[1] = (_Float16)raw[kt][rb][0].y;
            a[2] = (_Float16)raw[kt][rb][0].z; a[3] = (_Float16)raw[kt][rb][0].w;
            a[4] = (_Float16)raw[kt][rb][1].x; a[5] = (_Float16)raw[kt][rb][1].y;
            a[6] = (_Float16)raw[kt][rb][1].z; a[7] = (_Float16)raw[kt][rb][1].w;
            A[kt][rb] = a;
        }

    floatx4 acc[4][3];
#pragma unroll
    for (int nt = 0; nt < 4; nt++)
#pragma unroll
        for (int rb = 0; rb < 3; rb++) acc[nt][rb] = (floatx4){0, 0, 0, 0};

#pragma unroll
    for (int kt = 0; kt < NKT; kt++)
#pragma unroll
        for (int nt = 0; nt < 4; nt++) {
            const f16x8 b = Bs[(kt * 4 + nt) * 64 + lane];
#pragma unroll
            for (int rb = 0; rb < 3; rb++)
                acc[nt][rb] = __builtin_amdgcn_mfma_f32_16x16x32_f16(A[kt][rb], b, acc[nt][rb], 0, 0, 0);
        }

#pragma unroll
    for (int rb = 0; rb < 3; rb++) {
        float p1[4] = {0, 0, 0, 0}, p2[4] = {0, 0, 0, 0};
#pragma unroll
        for (int nt = 0; nt < 4; nt++)
#pragma unroll
            for (int reg = 0; reg < 4; reg++) {
                const int r = r0 + rb * 16 + quad * 4 + reg;
                if (r < n) H[(size_t)r * 64 + nt * 16 + l15] = (_Float16)acc[nt][rb][reg];
                p1[reg] = fmaf(acc[nt][rb][reg], a1c[nt], p1[reg]);
                p2[reg] = fmaf(acc[nt][rb][reg], a2c[nt], p2[reg]);
            }
#pragma unroll
        for (int m = 1; m < 16; m <<= 1)
#pragma unroll
            for (int reg = 0; reg < 4; reg++) {
                p1[reg] += __shfl_xor(p1[reg], m, 64);
                p2[reg] += __shfl_xor(p2[reg], m, 64);
            }
        if (l15 == 0)
#pragma unroll
            for (int reg = 0; reg < 4; reg++) {
                const int r = r0 + rb * 16 + quad * 4 + reg;
                if (r < n) { s1[r] = p1[reg]; s2[r] = p2[reg]; }
            }
    }
}

// ---------------- K3: h2 = Xm(fp16)[n,64] @ W2 -> fp16 + scores -------------
__global__ __launch_bounds__(256, 2) void gemm2_score(
    const _Float16* __restrict__ Xm, const float* __restrict__ W,
    const float* __restrict__ av, _Float16* __restrict__ H,
    float* __restrict__ s1, float* __restrict__ s2, int n)
{
    constexpr int NKT = 2;
    constexpr int NF = NKT * 4 * 64;
    __shared__ f16x8 Bs[NF];
    const int tid = threadIdx.x;

    for (int f = tid; f < NF; f += 256) {
        const int ln = f & 63, ntk = f >> 6;
        const int kt = ntk >> 2, nt = ntk & 3;
        const int kbase = kt * 32 + (ln >> 4) * 8;
        const int ccol = nt * 16 + (ln & 15);
        f16x8 hh;
#pragma unroll
        for (int j = 0; j < 8; j++)
            hh[j] = (_Float16)W[(kbase + j) * 64 + ccol];
        Bs[f] = hh;
    }
    __syncthreads();

    const int wave = tid >> 6, lane = tid & 63;
    const int quad = lane >> 4, l15 = lane & 15;
    const int r0 = blockIdx.x * 192 + wave * 48;

    f16x8 br[NKT][4];
#pragma unroll
    for (int kt = 0; kt < NKT; kt++)
#pragma unroll
        for (int nt = 0; nt < 4; nt++)
            br[kt][nt] = Bs[(kt * 4 + nt) * 64 + lane];

    float a1c[4], a2c[4];
#pragma unroll
    for (int nt = 0; nt < 4; nt++) {
        a1c[nt] = av[nt * 16 + l15];
        a2c[nt] = av[64 + nt * 16 + l15];
    }

    f16x8 A[NKT][3];
#pragma unroll
    for (int rb = 0; rb < 3; rb++) {
        int ra = r0 + rb * 16 + l15; if (ra > n - 1) ra = n - 1;
        const _Float16* xp = &Xm[(size_t)ra * 64 + quad * 8];
#pragma unroll
        for (int kt = 0; kt < NKT; kt++)
            A[kt][rb] = *(const f16x8*)(xp + kt * 32);
    }

    floatx4 acc[4][3];
#pragma unroll
    for (int nt = 0; nt < 4; nt++)
#pragma unroll
        for (int rb = 0; rb < 3; rb++) acc[nt][rb] = (floatx4){0, 0, 0, 0};

#pragma unroll
    for (int kt = 0; kt < NKT; kt++)
#pragma unroll
        for (int nt = 0; nt < 4; nt++)
#pragma unroll
            for (int rb = 0; rb < 3; rb++)
                acc[nt][rb] = __builtin_amdgcn_mfma_f32_16x16x32_f16(A[kt][rb], br[kt][nt], acc[nt][rb], 0, 0, 0);

#pragma unroll
    for (int rb = 0; rb < 3; rb++) {
        float p1[4] = {0, 0, 0, 0}, p2[4] = {0, 0, 0, 0};
#pragma unroll
        for (int nt = 0; nt < 4; nt++)
#pragma unroll
            for (int reg = 0; reg < 4; reg++) {
                const int r = r0 + rb * 16 + quad * 4 + reg;
                if (r < n) H[(size_t)r * 64 + nt * 16 + l15] = (_Float16)acc[nt][rb][reg];
                p1[reg] = fmaf(acc[nt][rb][reg], a1c[nt], p1[reg]);
                p2[reg] = fmaf(acc[nt][rb][reg], a2c[nt], p2[reg]);
            }
#pragma unroll
        for (int m = 1; m < 16; m <<= 1)
#pragma unroll
            for (int reg = 0; reg < 4; reg++) {
                p1[reg] += __shfl_xor(p1[reg], m, 64);
                p2[reg] += __shfl_xor(p2[reg], m, 64);
            }
        if (l15 == 0)
#pragma unroll
            for (int reg = 0; reg < 4; reg++) {
                const int r = r0 + rb * 16 + quad * 4 + reg;
                if (r < n) { s1[r] = p1[reg]; s2[r] = p2[reg]; }
            }
    }
}

// ---------------- K2/K4: attention, 4 nodes/wave, 16 lanes/node -------------
// lane = g*16+j; lane owns feats j*4..j*4+3; f16x4 gathers (8B/lane ->
// 512B/instr). Row gathers depend only on col-bpermute, so they are issued
// BEFORE the s2/softmax chain; scores compute while rows are in flight.
template<typename OT>
__global__ __launch_bounds__(512) void attn(
    const _Float16* __restrict__ H, const float* __restrict__ s1,
    const float* __restrict__ s2, const int* __restrict__ col,
    const float* __restrict__ bias, OT* __restrict__ out, int n)
{
    const int lane = threadIdx.x & 63;
    const int wv = threadIdx.x >> 6;
    const int j = lane & 15;
    const int dst = blockIdx.x * 32 + wv * 4 + (lane >> 4);
    const int dc = (dst > n - 1) ? (n - 1) : dst;

    const int c = col[dc * 16 + j];                  // coalesced

    // row indices (LDS-speed, independent of scores) -> issue gathers NOW
    const int bbase = (lane & 48) << 2;
    int srck[16];
#pragma unroll
    for (int k = 0; k < 16; k++)
        srck[k] = __builtin_amdgcn_ds_bpermute(bbase + (k << 2), c);
    f16x4 hv[16];
#pragma unroll
    for (int k = 0; k < 16; k++)
        hv[k] = *(const f16x4*)&H[(size_t)srck[k] * 64 + j * 4];

    // score chain overlaps the in-flight row gathers
    float e = s1[dc] + s2[c];
    e = (e > 0.0f) ? e : 0.2f * e;                   // leaky_relu 0.2
    float m = e;
#pragma unroll
    for (int mk = 1; mk < 16; mk <<= 1) m = fmaxf(m, __shfl_xor(m, mk, 64));
    float p = __expf(e - m);
    float s = p;
#pragma unroll
    for (int mk = 1; mk < 16; mk <<= 1) s += __shfl_xor(s, mk, 64);
    const float att = p / s;

    float attk[16];
#pragma unroll
    for (int k = 0; k < 16; k++)
        attk[k] = ubitf((unsigned)__builtin_amdgcn_ds_bpermute(bbase + (k << 2), (int)fbitu(att)));

    float a0 = 0, a1 = 0, a2 = 0, a3 = 0;
#pragma unroll
    for (int k = 0; k < 16; k++) {
        a0 = fmaf(attk[k], (float)hv[k][0], a0);
        a1 = fmaf(attk[k], (float)hv[k][1], a1);
        a2 = fmaf(attk[k], (float)hv[k][2], a2);
        a3 = fmaf(attk[k], (float)hv[k][3], a3);
    }
    if (dst < n) {
        const float4 bv = *(const float4*)&bias[j * 4];
        const float o0 = fmaxf(a0 + bv.x, 0.0f);
        const float o1 = fmaxf(a1 + bv.y, 0.0f);
        const float o2 = fmaxf(a2 + bv.z, 0.0f);
        const float o3 = fmaxf(a3 + bv.w, 0.0f);
        if constexpr (sizeof(OT) == 2) {
            f16x4 o; o[0] = (_Float16)o0; o[1] = (_Float16)o1;
                     o[2] = (_Float16)o2; o[3] = (_Float16)o3;
            *(f16x4*)&out[(size_t)dst * 64 + j * 4] = o;
        } else {
            float4 o; o.x = o0; o.y = o1; o.z = o2; o.w = o3;
            *(float4*)&out[(size_t)dst * 64 + j * 4] = o;
        }
    }
}

extern "C" void kernel_launch(void* const* d_in, const int* in_sizes, int n_in,
                              void* d_out, int out_size, void* d_ws, size_t ws_size,
                              hipStream_t stream)
{
    const float* x        = (const float*)d_in[0];
    const int*   edge_col = (const int*)  d_in[2];
    const float* W1       = (const float*)d_in[3];
    const float* a1       = (const float*)d_in[4];
    const float* b1       = (const float*)d_in[5];
    const float* W2       = (const float*)d_in[6];
    const float* a2       = (const float*)d_in[7];
    const float* b2       = (const float*)d_in[8];
    const int n = in_sizes[0] / 128;     // 100000

    _Float16* h1 = (_Float16*)d_ws;                  // n*64 fp16
    _Float16* xm = h1 + (size_t)n * 64;              // n*64 fp16
    _Float16* h2 = xm + (size_t)n * 64;              // n*64 fp16
    float* s1a = (float*)(h2 + (size_t)n * 64);      // n
    float* s2a = s1a + n;
    float* s1b = s2a + n;
    float* s2b = s1b + n;

    const int gemm_blocks = (n + 191) / 192;         // 521
    const int agg_blocks  = (n + 31) / 32;           // 3125

    gemm_score_f16<128><<<gemm_blocks, 256, 0, stream>>>(x, W1, a1, h1, s1a, s2a, n);
    attn<_Float16><<<agg_blocks, 512, 0, stream>>>(h1, s1a, s2a, edge_col, b1, xm, n);
    gemm2_score<<<gemm_blocks, 256, 0, stream>>>(xm, W2, a2, h2, s1b, s2b, n);
    attn<float><<<agg_blocks, 512, 0, stream>>>(h2, s1b, s2b, edge_col, b2, (float*)d_out, n);
}

// Round 11
// 183.694 us; speedup vs baseline: 1.0380x; 1.0380x over previous
//
#include <hip/hip_runtime.h>

// 2-layer GAT forward, N nodes, K=16 neighbors (row-sorted, exactly 16/dst),
// feats 128 -> 64 -> 64, fp32 in/out.  == R8 configuration (measured best) ==
//
// K1: h1 = x @ W1 (fp16 MFMA, single-precision-W) + scores s1a,s2a
// K2: attn(h1) -> xm fp16            [4 nodes/wave, 28-VGPR, max occupancy]
// K3: h2 = xm @ W2 + scores          [B operand entirely in registers]
// K4: attn(h2) -> out fp32
//
// Measured session notes (MI355X):
//  - R6: fusing attn+gemm cost occupancy (13%) -> net zero. Keep de-fused.
//  - R7: __launch_bounds__(256,4) strangled VGPRs -> serialized prefetch,
//    2.8x gemm1 regression. Keep (256,2) + 48-rows-upfront loads.
//  - R8: W-lo correction dropped; absmax 1.95e-3 vs 5.66e-3 threshold. BEST=184.3us.
//  - R9: 8-node/wave attn (120 VGPR) halved occupancy -> +6us. TLP > MLP here.
//  - R10: gather-before-softmax reorder neutral/negative -> compiler already
//    schedules VMEM; keep R8 order.
//  - Floor analysis: attn = 1.6M random 128B gathers (~30us/dispatch across
//    5 structural variants); gemms at BW floor; ~60-70us is harness re-poison
//    (268MB fills at 81% HBM peak), visible as the entire rocprof top-5.

typedef __attribute__((ext_vector_type(8))) _Float16 f16x8;
typedef __attribute__((ext_vector_type(4))) _Float16 f16x4;
typedef __attribute__((ext_vector_type(4))) float floatx4;

static __device__ inline float ubitf(unsigned u) { union { unsigned u; float f; } v; v.u = u; return v.f; }
static __device__ inline unsigned fbitu(float f) { union { float f; unsigned u; } v; v.f = f; return v.u; }

// ---------------- K1: h1 = X(fp32)[n,128] @ W1 -> fp16 + scores -------------
template<int KD>
__global__ __launch_bounds__(256, 2) void gemm_score_f16(
    const float* __restrict__ X, const float* __restrict__ W,
    const float* __restrict__ av, _Float16* __restrict__ H,
    float* __restrict__ s1, float* __restrict__ s2, int n)
{
    constexpr int NKT = KD / 32;
    constexpr int NF = NKT * 4 * 64;
    __shared__ f16x8 Bs[NF];
    const int tid = threadIdx.x;

    for (int f = tid; f < NF; f += 256) {
        const int ln = f & 63, ntk = f >> 6;
        const int kt = ntk >> 2, nt = ntk & 3;
        const int kbase = kt * 32 + (ln >> 4) * 8;
        const int ccol = nt * 16 + (ln & 15);
        f16x8 hh;
#pragma unroll
        for (int j = 0; j < 8; j++)
            hh[j] = (_Float16)W[(kbase + j) * 64 + ccol];
        Bs[f] = hh;
    }
    __syncthreads();

    const int wave = tid >> 6, lane = tid & 63;
    const int quad = lane >> 4, l15 = lane & 15;
    const int r0 = blockIdx.x * 192 + wave * 48;

    float a1c[4], a2c[4];
#pragma unroll
    for (int nt = 0; nt < 4; nt++) {
        a1c[nt] = av[nt * 16 + l15];
        a2c[nt] = av[64 + nt * 16 + l15];
    }

    float4 raw[NKT][3][2];
#pragma unroll
    for (int rb = 0; rb < 3; rb++) {
        int ra = r0 + rb * 16 + l15; if (ra > n - 1) ra = n - 1;
        const float* xp = &X[(size_t)ra * KD + quad * 8];
#pragma unroll
        for (int kt = 0; kt < NKT; kt++) {
            raw[kt][rb][0] = *(const float4*)(xp + kt * 32);
            raw[kt][rb][1] = *(const float4*)(xp + kt * 32 + 4);
        }
    }
    f16x8 A[NKT][3];
#pragma unroll
    for (int kt = 0; kt < NKT; kt++)
#pragma unroll
        for (int rb = 0; rb < 3; rb++) {
            f16x8 a;
            a[0] = (_Float16)raw[kt][rb][0].x; a[1] = (_Float16)raw[kt][rb][0].y;
            a[2] = (_Float16)raw[kt][rb][0].z; a[3] = (_Float16)raw[kt][rb][0].w;
            a[4] = (_Float16)raw[kt][rb][1].x; a[5] = (_Float16)raw[kt][rb][1].y;
            a[6] = (_Float16)raw[kt][rb][1].z; a[7] = (_Float16)raw[kt][rb][1].w;
            A[kt][rb] = a;
        }

    floatx4 acc[4][3];
#pragma unroll
    for (int nt = 0; nt < 4; nt++)
#pragma unroll
        for (int rb = 0; rb < 3; rb++) acc[nt][rb] = (floatx4){0, 0, 0, 0};

#pragma unroll
    for (int kt = 0; kt < NKT; kt++)
#pragma unroll
        for (int nt = 0; nt < 4; nt++) {
            const f16x8 b = Bs[(kt * 4 + nt) * 64 + lane];
#pragma unroll
            for (int rb = 0; rb < 3; rb++)
                acc[nt][rb] = __builtin_amdgcn_mfma_f32_16x16x32_f16(A[kt][rb], b, acc[nt][rb], 0, 0, 0);
        }

#pragma unroll
    for (int rb = 0; rb < 3; rb++) {
        float p1[4] = {0, 0, 0, 0}, p2[4] = {0, 0, 0, 0};
#pragma unroll
        for (int nt = 0; nt < 4; nt++)
#pragma unroll
            for (int reg = 0; reg < 4; reg++) {
                const int r = r0 + rb * 16 + quad * 4 + reg;
                if (r < n) H[(size_t)r * 64 + nt * 16 + l15] = (_Float16)acc[nt][rb][reg];
                p1[reg] = fmaf(acc[nt][rb][reg], a1c[nt], p1[reg]);
                p2[reg] = fmaf(acc[nt][rb][reg], a2c[nt], p2[reg]);
            }
#pragma unroll
        for (int m = 1; m < 16; m <<= 1)
#pragma unroll
            for (int reg = 0; reg < 4; reg++) {
                p1[reg] += __shfl_xor(p1[reg], m, 64);
                p2[reg] += __shfl_xor(p2[reg], m, 64);
            }
        if (l15 == 0)
#pragma unroll
            for (int reg = 0; reg < 4; reg++) {
                const int r = r0 + rb * 16 + quad * 4 + reg;
                if (r < n) { s1[r] = p1[reg]; s2[r] = p2[reg]; }
            }
    }
}

// ---------------- K3: h2 = Xm(fp16)[n,64] @ W2 -> fp16 + scores -------------
__global__ __launch_bounds__(256, 2) void gemm2_score(
    const _Float16* __restrict__ Xm, const float* __restrict__ W,
    const float* __restrict__ av, _Float16* __restrict__ H,
    float* __restrict__ s1, float* __restrict__ s2, int n)
{
    constexpr int NKT = 2;
    constexpr int NF = NKT * 4 * 64;
    __shared__ f16x8 Bs[NF];
    const int tid = threadIdx.x;

    for (int f = tid; f < NF; f += 256) {
        const int ln = f & 63, ntk = f >> 6;
        const int kt = ntk >> 2, nt = ntk & 3;
        const int kbase = kt * 32 + (ln >> 4) * 8;
        const int ccol = nt * 16 + (ln & 15);
        f16x8 hh;
#pragma unroll
        for (int j = 0; j < 8; j++)
            hh[j] = (_Float16)W[(kbase + j) * 64 + ccol];
        Bs[f] = hh;
    }
    __syncthreads();

    const int wave = tid >> 6, lane = tid & 63;
    const int quad = lane >> 4, l15 = lane & 15;
    const int r0 = blockIdx.x * 192 + wave * 48;

    f16x8 br[NKT][4];
#pragma unroll
    for (int kt = 0; kt < NKT; kt++)
#pragma unroll
        for (int nt = 0; nt < 4; nt++)
            br[kt][nt] = Bs[(kt * 4 + nt) * 64 + lane];

    float a1c[4], a2c[4];
#pragma unroll
    for (int nt = 0; nt < 4; nt++) {
        a1c[nt] = av[nt * 16 + l15];
        a2c[nt] = av[64 + nt * 16 + l15];
    }

    f16x8 A[NKT][3];
#pragma unroll
    for (int rb = 0; rb < 3; rb++) {
        int ra = r0 + rb * 16 + l15; if (ra > n - 1) ra = n - 1;
        const _Float16* xp = &Xm[(size_t)ra * 64 + quad * 8];
#pragma unroll
        for (int kt = 0; kt < NKT; kt++)
            A[kt][rb] = *(const f16x8*)(xp + kt * 32);
    }

    floatx4 acc[4][3];
#pragma unroll
    for (int nt = 0; nt < 4; nt++)
#pragma unroll
        for (int rb = 0; rb < 3; rb++) acc[nt][rb] = (floatx4){0, 0, 0, 0};

#pragma unroll
    for (int kt = 0; kt < NKT; kt++)
#pragma unroll
        for (int nt = 0; nt < 4; nt++)
#pragma unroll
            for (int rb = 0; rb < 3; rb++)
                acc[nt][rb] = __builtin_amdgcn_mfma_f32_16x16x32_f16(A[kt][rb], br[kt][nt], acc[nt][rb], 0, 0, 0);

#pragma unroll
    for (int rb = 0; rb < 3; rb++) {
        float p1[4] = {0, 0, 0, 0}, p2[4] = {0, 0, 0, 0};
#pragma unroll
        for (int nt = 0; nt < 4; nt++)
#pragma unroll
            for (int reg = 0; reg < 4; reg++) {
                const int r = r0 + rb * 16 + quad * 4 + reg;
                if (r < n) H[(size_t)r * 64 + nt * 16 + l15] = (_Float16)acc[nt][rb][reg];
                p1[reg] = fmaf(acc[nt][rb][reg], a1c[nt], p1[reg]);
                p2[reg] = fmaf(acc[nt][rb][reg], a2c[nt], p2[reg]);
            }
#pragma unroll
        for (int m = 1; m < 16; m <<= 1)
#pragma unroll
            for (int reg = 0; reg < 4; reg++) {
                p1[reg] += __shfl_xor(p1[reg], m, 64);
                p2[reg] += __shfl_xor(p2[reg], m, 64);
            }
        if (l15 == 0)
#pragma unroll
            for (int reg = 0; reg < 4; reg++) {
                const int r = r0 + rb * 16 + quad * 4 + reg;
                if (r < n) { s1[r] = p1[reg]; s2[r] = p2[reg]; }
            }
    }
}

// ---------------- K2/K4: attention, 4 nodes/wave, 16 lanes/node -------------
// lane = g*16+j; lane owns feats j*4..j*4+3; f16x4 gathers (8B/lane ->
// 512B/instr). 28 VGPR -> max occupancy; memory-latency-bound by design.
template<typename OT>
__global__ __launch_bounds__(512) void attn(
    const _Float16* __restrict__ H, const float* __restrict__ s1,
    const float* __restrict__ s2, const int* __restrict__ col,
    const float* __restrict__ bias, OT* __restrict__ out, int n)
{
    const int lane = threadIdx.x & 63;
    const int wv = threadIdx.x >> 6;
    const int j = lane & 15;
    const int dst = blockIdx.x * 32 + wv * 4 + (lane >> 4);
    if (dst >= n) return;

    const int c = col[dst * 16 + j];                 // coalesced
    float e = s1[dst] + s2[c];
    e = (e > 0.0f) ? e : 0.2f * e;                   // leaky_relu 0.2
    float m = e;
#pragma unroll
    for (int mk = 1; mk < 16; mk <<= 1) m = fmaxf(m, __shfl_xor(m, mk, 64));
    float p = __expf(e - m);
    float s = p;
#pragma unroll
    for (int mk = 1; mk < 16; mk <<= 1) s += __shfl_xor(s, mk, 64);
    const float att = p / s;

    const int bbase = (lane & 48) << 2;
    int srck[16]; float attk[16];
#pragma unroll
    for (int k = 0; k < 16; k++) {
        const int bidx = bbase + (k << 2);
        srck[k] = __builtin_amdgcn_ds_bpermute(bidx, c);
        attk[k] = ubitf((unsigned)__builtin_amdgcn_ds_bpermute(bidx, (int)fbitu(att)));
    }
    f16x4 hv[16];
#pragma unroll
    for (int k = 0; k < 16; k++)
        hv[k] = *(const f16x4*)&H[(size_t)srck[k] * 64 + j * 4];

    float a0 = 0, a1 = 0, a2 = 0, a3 = 0;
#pragma unroll
    for (int k = 0; k < 16; k++) {
        a0 = fmaf(attk[k], (float)hv[k][0], a0);
        a1 = fmaf(attk[k], (float)hv[k][1], a1);
        a2 = fmaf(attk[k], (float)hv[k][2], a2);
        a3 = fmaf(attk[k], (float)hv[k][3], a3);
    }
    const float4 bv = *(const float4*)&bias[j * 4];
    const float o0 = fmaxf(a0 + bv.x, 0.0f);
    const float o1 = fmaxf(a1 + bv.y, 0.0f);
    const float o2 = fmaxf(a2 + bv.z, 0.0f);
    const float o3 = fmaxf(a3 + bv.w, 0.0f);
    if constexpr (sizeof(OT) == 2) {
        f16x4 o; o[0] = (_Float16)o0; o[1] = (_Float16)o1;
                 o[2] = (_Float16)o2; o[3] = (_Float16)o3;
        *(f16x4*)&out[(size_t)dst * 64 + j * 4] = o;
    } else {
        float4 o; o.x = o0; o.y = o1; o.z = o2; o.w = o3;
        *(float4*)&out[(size_t)dst * 64 + j * 4] = o;
    }
}

extern "C" void kernel_launch(void* const* d_in, const int* in_sizes, int n_in,
                              void* d_out, int out_size, void* d_ws, size_t ws_size,
                              hipStream_t stream)
{
    const float* x        = (const float*)d_in[0];
    const int*   edge_col = (const int*)  d_in[2];
    const float* W1       = (const float*)d_in[3];
    const float* a1       = (const float*)d_in[4];
    const float* b1       = (const float*)d_in[5];
    const float* W2       = (const float*)d_in[6];
    const float* a2       = (const float*)d_in[7];
    const float* b2       = (const float*)d_in[8];
    const int n = in_sizes[0] / 128;     // 100000

    _Float16* h1 = (_Float16*)d_ws;                  // n*64 fp16
    _Float16* xm = h1 + (size_t)n * 64;              // n*64 fp16
    _Float16* h2 = xm + (size_t)n * 64;              // n*64 fp16
    float* s1a = (float*)(h2 + (size_t)n * 64);      // n
    float* s2a = s1a + n;
    float* s1b = s2a + n;
    float* s2b = s1b + n;

    const int gemm_blocks = (n + 191) / 192;         // 521
    const int agg_blocks  = (n + 31) / 32;           // 3125

    gemm_score_f16<128><<<gemm_blocks, 256, 0, stream>>>(x, W1, a1, h1, s1a, s2a, n);
    attn<_Float16><<<agg_blocks, 512, 0, stream>>>(h1, s1a, s2a, edge_col, b1, xm, n);
    gemm2_score<<<gemm_blocks, 256, 0, stream>>>(xm, W2, a2, h2, s1b, s2b, n);
    attn<float><<<agg_blocks, 512, 0, stream>>>(h2, s1b, s2b, edge_col, b2, (float*)d_out, n);
}